// Round 7
// baseline (50.578 us; speedup 1.0000x reference)
//
#include <hip/hip_runtime.h>
#include <hip/hip_bf16.h>

typedef float f32x4 __attribute__((ext_vector_type(4)));
typedef _Float16 f16x2 __attribute__((ext_vector_type(2)));
typedef _Float16 f16x8 __attribute__((ext_vector_type(8)));

#define CC   64
#define HID  256
#define NOUT 64
#define HOUT 384
#define MAXCELL 8
#define CELLB 544                 // 512 data + 32 pad
#define UVB  (MAXCELL * CELLB)    // 4352
#define W2B  (UVB + 1024)         // 5376
#define SMEMB (W2B + 32768)       // 38144 bytes -> 4 blocks/CU max, we use 3
#define NBLK 768
#define TILES 6                   // 768 * 6 = 4608 tiles

__device__ __forceinline__ int corner_cell(float cq, float sh) {
    float c = cq + sh + 1e-6f;
    c = fminf(fmaxf(c, -1.f + 1e-6f), 1.f - 1e-6f);
    int i = (int)roundf(((c + 1.f) * 64.f - 1.f) * 0.5f);
    return min(max(i, 0), 63);
}

// ---- k_prep: shuffle w2 -> W2F frags, w1[0:64] -> W1F frags, w1[64:66] -> UVH f16
__global__ __launch_bounds__(256) void k_prep(const float* __restrict__ w1,
                                              const float* __restrict__ w2,
                                              _Float16* __restrict__ W2F,
                                              _Float16* __restrict__ W1F,
                                              _Float16* __restrict__ UVH) {
    int idx = blockIdx.x * 256 + threadIdx.x;
    if (idx < 16384) {
        int f = idx, e = f & 7, l = (f >> 3) & 63, grp = f >> 9;
        int ks = grp >> 2, ng = grp & 3;
        int k = ks * 32 + ((l >> 4) << 3) + e;
        int n = (ng << 4) + (l & 15);
        W2F[f] = (_Float16)w2[k * NOUT + n];
    } else if (idx < 32768) {
        int f = idx - 16384, e = f & 7, l = (f >> 3) & 63, grp = f >> 9;
        int ks = grp >> 4, ng = grp & 15;
        int k = ks * 32 + ((l >> 4) << 3) + e;
        int n = (ng << 4) + (l & 15);
        W1F[f] = (_Float16)w1[k * HID + n];
    } else if (idx < 32768 + 512) {
        int f = idx - 32768;
        UVH[f] = (_Float16)w1[(CC + (f >> 8)) * HID + (f & 255)];
    }
}

// ---- k_gfeat (MFMA): G[cell][n] = b1[n] + sum_c res_f16[cell][c] * w1_f16[c][n]
__global__ __launch_bounds__(256) void k_gfeat(const float* __restrict__ res,
                                               const _Float16* __restrict__ W1F,
                                               const float* __restrict__ b1,
                                               _Float16* __restrict__ G) {
    const int cell0 = blockIdx.x * 32;
    const int b = cell0 >> 12, iyix0 = cell0 & 4095;
    const int tid = threadIdx.x;
    __shared__ _Float16 lds_a[32][72];
    __shared__ _Float16 lds_d[32][264];

    {
        int c = tid >> 2, cs = (tid & 3) * 8;
        const float* src = res + (((b * CC + c) << 12) + iyix0 + cs);
        f32x4 r0 = *(const f32x4*)src;
        f32x4 r1 = *(const f32x4*)(src + 4);
#pragma unroll
        for (int e = 0; e < 4; ++e) lds_a[cs + e][c] = (_Float16)r0[e];
#pragma unroll
        for (int e = 0; e < 4; ++e) lds_a[cs + 4 + e][c] = (_Float16)r1[e];
    }
    __syncthreads();

    const int wv = tid >> 6, l = tid & 63, lhi = l >> 4, dj = l & 15;
    const int crow = (wv & 1) * 16;
    const int nh = (wv >> 1) * 8;

    f32x4 acc[8];
#pragma unroll
    for (int q = 0; q < 8; ++q) {
        float bb = b1[(nh + q) * 16 + dj];
        acc[q] = (f32x4){bb, bb, bb, bb};
    }
#pragma unroll
    for (int ks = 0; ks < 2; ++ks) {
        f16x8 afr = *(const f16x8*)&lds_a[crow + dj][ks * 32 + lhi * 8];
#pragma unroll
        for (int q = 0; q < 8; ++q) {
            f16x8 bfr = *(const f16x8*)(W1F + (((ks * 16 + nh + q) * 64 + l) << 3));
            acc[q] = __builtin_amdgcn_mfma_f32_16x16x32_f16(afr, bfr, acc[q], 0, 0, 0);
        }
    }
#pragma unroll
    for (int q = 0; q < 8; ++q) {
        int n = (nh + q) * 16 + dj;
#pragma unroll
        for (int r = 0; r < 4; ++r)
            lds_d[crow + lhi * 4 + r][n] = (_Float16)acc[q][r];
    }
    __syncthreads();
    {
        int cell = tid >> 3, ch = (tid & 7) * 32;
        _Float16* dst = G + (((size_t)(cell0 + cell)) << 8) + ch;
#pragma unroll
        for (int r = 0; r < 4; ++r)
            *(f32x4*)(dst + r * 8) = *(const f32x4*)&lds_d[cell][ch + r * 8];
    }
}

struct TileP { int it, jt, b, r0, c0, nc, ncell; };

__device__ __forceinline__ TileP tile_params(int tt) {
    TileP tp;
    tp.b = tt / 2304;
    int rem = tt - tp.b * 2304;
    tp.it = rem / 24;
    tp.jt = rem - tp.it * 24;
    const int i0 = tp.it * 4, j0 = tp.jt * 16;
    const float S = 1.f / 384.f;
    tp.r0 = corner_cell(-1.f + (2 * i0 + 1) / 384.f, -S);
    int r1 = corner_cell(-1.f + (2 * (i0 + 3) + 1) / 384.f, +S);
    tp.c0 = corner_cell(-1.f + (2 * j0 + 1) / 384.f, -S);
    int c1 = corner_cell(-1.f + (2 * (j0 + 15) + 1) / 384.f, +S);
    tp.nc = c1 - tp.c0 + 1;
    tp.ncell = (r1 - tp.r0 + 1) * tp.nc;
    return tp;
}

__device__ __forceinline__ f32x4 cell_prefetch(const _Float16* __restrict__ G,
                                               const TileP& tp, int cellid, int c16) {
    f32x4 v = {};
    if (cellid < tp.ncell) {
        float rcp = 1.f / (float)tp.nc;
        int cr = (int)((float)cellid * rcp);
        int cc2 = cellid - cr * tp.nc;
        v = *(const f32x4*)(G + (((size_t)((tp.b << 12) + ((tp.r0 + cr) << 6) + (tp.c0 + cc2))) << 8) + (c16 << 3));
    }
    return v;
}

// ---- main: 768 persistent blocks x 6 tiles. W2F+uv staged ONCE; per tile only
// 4 KB of cells (1 f32x4 load + 1 ds_write per thread), prefetched a tile ahead
// and kept in flight across a raw lgkm-only barrier.
__global__ __launch_bounds__(256, 4) void k_main(const _Float16* __restrict__ G,
                                                 const _Float16* __restrict__ W2F,
                                                 const _Float16* __restrict__ UVH,
                                                 const float* __restrict__ b2,
                                                 float* __restrict__ out) {
    const int tid = threadIdx.x;
    const int wv = tid >> 6, l = tid & 63;
    const int lhi = l >> 4, dj = l & 15;

    __shared__ char smem[SMEMB];

    // one-time stage: uv + W2F
    if (tid < 64)
        *(f32x4*)(smem + UVB + (tid << 4)) = *(const f32x4*)(UVH + (tid << 3));
    {
        const f32x4* w2g = (const f32x4*)W2F;
#pragma unroll
        for (int t = 0; t < 8; ++t)
            *(f32x4*)(smem + W2B + ((t * 256 + tid) << 4)) = w2g[t * 256 + tid];
    }
    float bbv[4];
#pragma unroll
    for (int ng = 0; ng < 4; ++ng) bbv[ng] = b2[(ng << 4) + dj];

    const int cellid = tid >> 5, c16 = tid & 31;
    char* sdst = smem + cellid * CELLB + (c16 << 4);
    const int lo16 = lhi << 4;
    const char* uvp = smem + UVB + lo16;
    const f16x8* w2l = (const f16x8*)(smem + W2B) + l;
    const float S = 1.f / 384.f;

    TileP tp = tile_params(blockIdx.x);
    f32x4 pf = cell_prefetch(G, tp, cellid, c16);

    for (int s = 0; s < TILES; ++s) {
        // B1: previous tile's LDS reads done -> safe to overwrite cells
        asm volatile("s_waitcnt lgkmcnt(0)" ::: "memory");
        __builtin_amdgcn_s_barrier();
        __builtin_amdgcn_sched_barrier(0);
        if (cellid < tp.ncell) *(f32x4*)sdst = pf;
        TileP tpn = tp;
        if (s + 1 < TILES) {
            tpn = tile_params(blockIdx.x + (s + 1) * NBLK);
            pf = cell_prefetch(G, tpn, cellid, c16);   // stays in flight across B2
        }
        // B2: cells visible to all waves; do NOT drain vmcnt (prefetch in flight)
        asm volatile("s_waitcnt lgkmcnt(0)" ::: "memory");
        __builtin_amdgcn_s_barrier();
        __builtin_amdgcn_sched_barrier(0);

        // ---- compute tile tp ----
        const int i0 = tp.it * 4, j0 = tp.jt * 16;
        const int i = i0 + wv, j = j0 + dj;
        const float cyq = -1.f + (2 * i + 1) / 384.f;
        const float cxq = -1.f + (2 * j + 1) / 384.f;
        const int iym = corner_cell(cyq, -S), iyp = corner_cell(cyq, +S);
        const int ixm = corner_cell(cxq, -S), ixp = corner_cell(cxq, +S);
        const float ry0 = (cyq - (-1.f + (2 * iym + 1) / 64.f)) * 64.f;
        const float ry1 = (cyq - (-1.f + (2 * iyp + 1) / 64.f)) * 64.f;
        const float rx0 = (cxq - (-1.f + (2 * ixm + 1) / 64.f)) * 64.f;
        const float rx1 = (cxq - (-1.f + (2 * ixp + 1) / 64.f)) * 64.f;
        const bool ys = (iyp != iym), xs = (ixp != ixm);
        const float a0 = fabsf(ry0 * rx0) + 1e-9f;
        const float a1 = fabsf(ry0 * (xs ? rx1 : rx0)) + 1e-9f;
        const float a2 = fabsf((ys ? ry1 : ry0) * rx0) + 1e-9f;
        const float a3 = fabsf((ys ? ry1 : ry0) * (xs ? rx1 : rx0)) + 1e-9f;
        const float inv = 1.f / (a0 + a1 + a2 + a3);
        const float g0w = a3 * inv, g1w = a2 * inv, g2w = a1 * inv, g3w = a0 * inv;
        float W00 = g0w, W01 = 0.f, W10 = 0.f, W11 = 0.f;
        if (xs) W01 += g1w; else W00 += g1w;
        if (ys) W10 += g2w; else W00 += g2w;
        if (ys && xs) W11 += g3w;
        else if (ys)  W10 += g3w;
        else if (xs)  W01 += g3w;
        else          W00 += g3w;

#define DUP2(x) (f16x2){(_Float16)(x), (_Float16)(x)}
        const f16x2 ry0h = DUP2(ry0), ry1h = DUP2(ry1);
        const f16x2 rx0h = DUP2(rx0), rx1h = DUP2(rx1);
        const f16x2 W00h = DUP2(W00), W01h = DUP2(W01);
        const f16x2 W10h = DUP2(W10), W11h = DUP2(W11);

        const char* cell00 = smem + ((iym - tp.r0) * tp.nc + (ixm - tp.c0)) * CELLB + lo16;
        const char* cell01 = smem + ((iym - tp.r0) * tp.nc + (ixp - tp.c0)) * CELLB + lo16;
        const char* cell10 = smem + ((iyp - tp.r0) * tp.nc + (ixm - tp.c0)) * CELLB + lo16;
        const char* cell11 = smem + ((iyp - tp.r0) * tp.nc + (ixp - tp.c0)) * CELLB + lo16;

        f32x4 acc[4];
#pragma unroll
        for (int ng = 0; ng < 4; ++ng) acc[ng] = (f32x4){0.f, 0.f, 0.f, 0.f};

#define NODE(cp, ryh, rxh, Wh) {                                           \
        f16x8 gv = *(const f16x8*)((cp) + ko);                             \
        f16x2 g2;                                                          \
        _Pragma("unroll")                                                  \
        for (int e = 0; e < 4; ++e) {                                      \
            g2[0] = gv[2*e]; g2[1] = gv[2*e+1];                            \
            f16x2 t = g2 + (ryh) * uu[e] + (rxh) * vv[e];                  \
            t = __builtin_elementwise_max(t, (f16x2){(_Float16)0.f, (_Float16)0.f}); \
            h[e] += (Wh) * t;                                              \
        } }

#pragma unroll
        for (int ks = 0; ks < 8; ++ks) {
            const int ko = ks * 64;
            f16x8 uraw = *(const f16x8*)(uvp + ko);
            f16x8 vraw = *(const f16x8*)(uvp + 512 + ko);
            f16x2 uu[4], vv[4];
#pragma unroll
            for (int e = 0; e < 4; ++e) {
                uu[e][0] = uraw[2*e]; uu[e][1] = uraw[2*e+1];
                vv[e][0] = vraw[2*e]; vv[e][1] = vraw[2*e+1];
            }
            f16x2 h[4] = {};
            NODE(cell00, ry0h, rx0h, W00h);
            NODE(cell01, ry0h, rx1h, W01h);
            if (ys) {
                NODE(cell10, ry1h, rx0h, W10h);
                NODE(cell11, ry1h, rx1h, W11h);
            }
            f16x8 af;
#pragma unroll
            for (int e = 0; e < 4; ++e) { af[2*e] = h[e][0]; af[2*e+1] = h[e][1]; }
#pragma unroll
            for (int ng = 0; ng < 4; ++ng)
                acc[ng] = __builtin_amdgcn_mfma_f32_16x16x32_f16(af, w2l[(ks * 4 + ng) * 64], acc[ng], 0, 0, 0);
        }
#undef NODE

        // epilogue: direct stores
#pragma unroll
        for (int ng = 0; ng < 4; ++ng) {
            const int o = (ng << 4) + dj;
            float* op = out + (((size_t)tp.b * NOUT + o) * HOUT + i) * HOUT + j0 + (lhi << 2);
#pragma unroll
            for (int r = 0; r < 4; ++r)
                op[r] = acc[ng][r] + bbv[ng];
        }
        tp = tpn;
    }
}

extern "C" void kernel_launch(void* const* d_in, const int* in_sizes, int n_in,
                              void* d_out, int out_size, void* d_ws, size_t ws_size,
                              hipStream_t stream) {
    const float* res = (const float*)d_in[0];
    const float* w1  = (const float*)d_in[1];
    const float* b1  = (const float*)d_in[2];
    const float* w2  = (const float*)d_in[3];
    const float* b2  = (const float*)d_in[4];
    float* out = (float*)d_out;

    char* ws = (char*)d_ws;
    _Float16* G   = (_Float16*)ws;                              // 4 MB
    _Float16* W2F = (_Float16*)(ws + (size_t)(8u << 20));       // 32 KB
    _Float16* W1F = (_Float16*)(ws + (size_t)(8u << 20) + 65536);
    _Float16* UVH = (_Float16*)(ws + (size_t)(8u << 20) + 131072);

    k_prep<<<130, 256, 0, stream>>>(w1, w2, W2F, W1F, UVH);
    k_gfeat<<<256, 256, 0, stream>>>(res, W1F, b1, G);
    k_main<<<NBLK, 256, 0, stream>>>(G, W2F, UVH, b2, out);
}